// Round 6
// baseline (138.915 us; speedup 1.0000x reference)
//
#include <hip/hip_runtime.h>
#include <hip/hip_fp16.h>

// UVRenderer round 6: quad-texel table (one cache line per pixel gather), with
// pack/render interleaved in 2-batch chunks so the just-written table chunk
// (64 MB) stays L3-resident while its render pass gathers from it.
// Fixed dims: B=4, H=W=Ht=Wt=1024, F=40000.

#define BB    4
#define HWT   (1 << 20)
#define WMASK 1023
#define HHALF (HWT / 2)

static __device__ __forceinline__ unsigned h2b(float a, float b) {
    __half2 h = __floats2half2_rn(a, b);
    return *reinterpret_cast<const unsigned*>(&h);
}
static __device__ __forceinline__ float2 h2f(unsigned u) {
    return __half22float2(*reinterpret_cast<const __half2*>(&u));
}

__global__ __launch_bounds__(256) void build_ftab(
    const int* __restrict__ face_uv, const float* __restrict__ vertex_uv,
    float4* __restrict__ ftab, int F)
{
    const int f = blockIdx.x * blockDim.x + threadIdx.x;
    if (f >= F) return;
    const int i0 = face_uv[f * 3 + 0];
    const int i1 = face_uv[f * 3 + 1];
    const int i2 = face_uv[f * 3 + 2];
    float4 a, b;
    a.x = vertex_uv[i0 * 2 + 0]; a.y = 1.0f - vertex_uv[i0 * 2 + 1];
    a.z = vertex_uv[i1 * 2 + 0]; a.w = 1.0f - vertex_uv[i1 * 2 + 1];
    b.x = vertex_uv[i2 * 2 + 0]; b.y = 1.0f - vertex_uv[i2 * 2 + 1];
    b.z = 0.0f; b.w = 0.0f;
    ftab[f * 2 + 0] = a;
    ftab[f * 2 + 1] = b;
}

// Packs batches [b0, b0+1] of the quad table.
template <bool PAD32>
__global__ __launch_bounds__(256) void pack_quad_chunk(
    const float* __restrict__ uvmap, unsigned* __restrict__ ptexu, int b0)
{
    const int t = blockIdx.x * blockDim.x + threadIdx.x;  // 2M
    const int b  = b0 + (t >> 20);
    const int hw = t & (HWT - 1);
    const int i  = (b << 20) | hw;  // global table entry index
    const int x  = hw & WMASK;
    const int y  = hw >> 10;
    const int xr = min(x + 1, WMASK);
    const int yd = min(y + 1, WMASK);
    const float* base = uvmap + ((size_t)b * 3 << 20);
    const int iTL = (y  << 10) | x,  iTR = (y  << 10) | xr;
    const int iBL = (yd << 10) | x,  iBR = (yd << 10) | xr;
    const float c0TL = base[iTL],           c0TR = base[iTR];
    const float c1TL = base[HWT + iTL],     c1TR = base[HWT + iTR];
    const float c2TL = base[2 * HWT + iTL], c2TR = base[2 * HWT + iTR];
    const float c0BL = base[iBL],           c0BR = base[iBR];
    const float c1BL = base[HWT + iBL],     c1BR = base[HWT + iBR];
    const float c2BL = base[2 * HWT + iBL], c2BR = base[2 * HWT + iBR];

    const unsigned t0 = h2b(c0TL, c1TL), t1 = h2b(c2TL, c0TR), t2 = h2b(c1TR, c2TR);
    const unsigned u0 = h2b(c0BL, c1BL), u1 = h2b(c2BL, c0BR), u2 = h2b(c1BR, c2BR);

    if (PAD32) {
        uint4* p = reinterpret_cast<uint4*>(ptexu);
        uint4 a; a.x = t0; a.y = t1; a.z = t2; a.w = 0u;
        uint4 c; c.x = u0; c.y = u1; c.z = u2; c.w = 0u;
        p[(size_t)i * 2 + 0] = a;
        p[(size_t)i * 2 + 1] = c;
    } else {
        const size_t o = (size_t)i * 6;
        ptexu[o + 0] = t0; ptexu[o + 1] = t1; ptexu[o + 2] = t2;
        ptexu[o + 3] = u0; ptexu[o + 4] = u1; ptexu[o + 5] = u2;
    }
}

// Renders batches [b0, b0+1]; each thread does 4 pixels (2 per batch).
template <bool PAD32>
__global__ __launch_bounds__(256) void render_chunk(
    const unsigned* __restrict__ ptexu, const float4* __restrict__ ftab,
    const float* __restrict__ bary, const int* __restrict__ pix,
    const float* __restrict__ bkg, int F,
    float* __restrict__ render, float* __restrict__ is_valid, int b0)
{
    const int tid = blockIdx.x * blockDim.x + threadIdx.x;  // 512K
    const float bkg0 = bkg[0], bkg1 = bkg[1], bkg2 = bkg[2];

    int idx[4], bj[4];
    #pragma unroll
    for (int j = 0; j < 4; ++j) {
        bj[j]  = b0 + (j >> 1);
        idx[j] = (bj[j] << 20) | (tid + ((j & 1) ? HHALF : 0));
    }

    int pf[4];
    #pragma unroll
    for (int j = 0; j < 4; ++j)
        pf[j] = __builtin_nontemporal_load(&pix[idx[j]]);

    float ba[4][3];
    #pragma unroll
    for (int j = 0; j < 4; ++j) {
        const size_t o = (size_t)idx[j] * 3;
        ba[j][0] = __builtin_nontemporal_load(&bary[o + 0]);
        ba[j][1] = __builtin_nontemporal_load(&bary[o + 1]);
        ba[j][2] = __builtin_nontemporal_load(&bary[o + 2]);
    }

    float4 A[4], Bv[4];
    #pragma unroll
    for (int j = 0; j < 4; ++j) {
        const int lf = (pf[j] != -1) ? pf[j] - bj[j] * F : 0;
        A[j]  = ftab[lf * 2 + 0];
        Bv[j] = ftab[lf * 2 + 1];
    }

    unsigned t0[4], t1[4], t2[4], u0[4], u1[4], u2[4];
    float wx[4], wy[4];
    #pragma unroll
    for (int j = 0; j < 4; ++j) {
        const float u = ba[j][0] * A[j].x + ba[j][1] * A[j].z + ba[j][2] * Bv[j].x;
        const float v = ba[j][0] * A[j].y + ba[j][1] * A[j].w + ba[j][2] * Bv[j].y;
        float x = fminf(fmaxf(u * 1023.0f, 0.0f), 1023.0f);
        float y = fminf(fmaxf(v * 1023.0f, 0.0f), 1023.0f);
        if (pf[j] == -1) { x = 0.0f; y = 0.0f; }
        const float xf = floorf(x), yf = floorf(y);
        wx[j] = x - xf; wy[j] = y - yf;
        const int e = (bj[j] << 20) | (((int)yf) << 10) | (int)xf;
        if (PAD32) {
            const uint4* p = reinterpret_cast<const uint4*>(ptexu);
            const uint4 qt = p[(size_t)e * 2 + 0];
            const uint4 qb = p[(size_t)e * 2 + 1];
            t0[j] = qt.x; t1[j] = qt.y; t2[j] = qt.z;
            u0[j] = qb.x; u1[j] = qb.y; u2[j] = qb.z;
        } else {
            const size_t o = (size_t)e * 6;
            t0[j] = ptexu[o + 0]; t1[j] = ptexu[o + 1]; t2[j] = ptexu[o + 2];
            u0[j] = ptexu[o + 3]; u1[j] = ptexu[o + 4]; u2[j] = ptexu[o + 5];
        }
    }

    #pragma unroll
    for (int j = 0; j < 4; ++j) {
        const float2 a01 = h2f(t0[j]), a2b = h2f(t1[j]), a12 = h2f(t2[j]);
        const float2 c01 = h2f(u0[j]), c2b = h2f(u1[j]), c12 = h2f(u2[j]);
        const float iwx = 1.0f - wx[j], iwy = 1.0f - wy[j];
        const float top0 = a01.x * iwx + a2b.y * wx[j];
        const float top1 = a01.y * iwx + a12.x * wx[j];
        const float top2 = a2b.x * iwx + a12.y * wx[j];
        const float bot0 = c01.x * iwx + c2b.y * wx[j];
        const float bot1 = c01.y * iwx + c12.x * wx[j];
        const float bot2 = c2b.x * iwx + c12.y * wx[j];
        float r0 = top0 * iwy + bot0 * wy[j];
        float r1 = top1 * iwy + bot1 * wy[j];
        float r2 = top2 * iwy + bot2 * wy[j];
        float vf = 1.0f;
        if (pf[j] == -1) { r0 = bkg0; r1 = bkg1; r2 = bkg2; vf = 0.0f; }
        const int hwj = idx[j] & (HWT - 1);
        const int ob  = (bj[j] * 3) << 20;
        __builtin_nontemporal_store(r0, &render[ob + hwj]);
        __builtin_nontemporal_store(r1, &render[ob + HWT + hwj]);
        __builtin_nontemporal_store(r2, &render[ob + 2 * HWT + hwj]);
        __builtin_nontemporal_store(vf, &is_valid[idx[j]]);
    }
}

// ---------- no-workspace safety fallback (direct planar gather) ----------
__global__ __launch_bounds__(256) void uvrender_direct(
    const float* __restrict__ bary, const float* __restrict__ uvmap,
    const float* __restrict__ vertex_uv, const float* __restrict__ bkg,
    const int* __restrict__ pix_to_face, const int* __restrict__ face_uv,
    int F, float* __restrict__ render, float* __restrict__ is_valid)
{
    const int total = BB * HWT;
    const float bkg0 = bkg[0], bkg1 = bkg[1], bkg2 = bkg[2];
    for (int idx = blockIdx.x * blockDim.x + threadIdx.x; idx < total;
         idx += gridDim.x * blockDim.x) {
        const int b  = idx >> 20;
        const int hw = idx & (HWT - 1);
        const int pf = pix_to_face[idx];
        float r0 = bkg0, r1 = bkg1, r2 = bkg2, vflag = 0.0f;
        if (pf != -1) {
            vflag = 1.0f;
            const int local = pf - b * F;
            const int i0 = face_uv[local * 3 + 0];
            const int i1 = face_uv[local * 3 + 1];
            const int i2 = face_uv[local * 3 + 2];
            const float b0 = bary[(size_t)idx * 3 + 0];
            const float b1 = bary[(size_t)idx * 3 + 1];
            const float b2 = bary[(size_t)idx * 3 + 2];
            const float u = b0 * vertex_uv[i0 * 2] + b1 * vertex_uv[i1 * 2] +
                            b2 * vertex_uv[i2 * 2];
            const float v = b0 * (1.0f - vertex_uv[i0 * 2 + 1]) +
                            b1 * (1.0f - vertex_uv[i1 * 2 + 1]) +
                            b2 * (1.0f - vertex_uv[i2 * 2 + 1]);
            float x = fminf(fmaxf(u * 1023.0f, 0.0f), 1023.0f);
            float y = fminf(fmaxf(v * 1023.0f, 0.0f), 1023.0f);
            const float xf = floorf(x), yf = floorf(y);
            const int x0 = (int)xf, y0 = (int)yf;
            const int x1 = min(x0 + 1, WMASK), y1 = min(y0 + 1, WMASK);
            const float wxx = x - xf, wyy = y - yf;
            const float iwx = 1.0f - wxx, iwy = 1.0f - wyy;
            const float* texb = uvmap + ((size_t)b * 3 << 20);
            float out[3];
            #pragma unroll
            for (int c = 0; c < 3; ++c) {
                const float* t = texb + ((size_t)c << 20);
                const float t00 = t[(y0 << 10) | x0];
                const float t01 = t[(y0 << 10) | x1];
                const float t10 = t[(y1 << 10) | x0];
                const float t11 = t[(y1 << 10) | x1];
                out[c] = (t00 * iwx + t01 * wxx) * iwy + (t10 * iwx + t11 * wxx) * wyy;
            }
            r0 = out[0]; r1 = out[1]; r2 = out[2];
        }
        const size_t ob = (size_t)b * 3 * HWT + hw;
        __builtin_nontemporal_store(r0, &render[ob]);
        __builtin_nontemporal_store(r1, &render[ob + HWT]);
        __builtin_nontemporal_store(r2, &render[ob + 2 * (size_t)HWT]);
        __builtin_nontemporal_store(vflag, &is_valid[idx]);
    }
}

extern "C" void kernel_launch(void* const* d_in, const int* in_sizes, int n_in,
                              void* d_out, int out_size, void* d_ws, size_t ws_size,
                              hipStream_t stream) {
    const float* bary        = (const float*)d_in[0];
    const float* uvmap       = (const float*)d_in[1];
    const float* vertex_uv   = (const float*)d_in[2];
    const float* bkg         = (const float*)d_in[3];
    const int*   pix_to_face = (const int*)d_in[4];
    const int*   face_uv     = (const int*)d_in[5];
    const int F = in_sizes[5] / 3;   // 40000

    float* render   = (float*)d_out;
    float* is_valid = (float*)d_out + (size_t)BB * 3 * HWT;

    const size_t Q32_B  = (size_t)BB * HWT * 32;            // 128 MiB
    const size_t Q24_B  = (size_t)BB * HWT * 24;            //  96 MiB
    const size_t FTAB_B = (size_t)F * 2 * sizeof(float4);   // ~1.25 MiB

    if (ws_size >= Q32_B + FTAB_B) {
        unsigned* ptexu = (unsigned*)d_ws;
        float4*   ftab  = (float4*)((char*)d_ws + Q32_B);
        build_ftab<<<(F + 255) / 256, 256, 0, stream>>>(face_uv, vertex_uv, ftab, F);
        for (int c = 0; c < 2; ++c) {
            pack_quad_chunk<true><<<(2 * HWT) / 256, 256, 0, stream>>>(uvmap, ptexu, c * 2);
            render_chunk<true><<<HHALF / 256, 256, 0, stream>>>(
                ptexu, ftab, bary, pix_to_face, bkg, F, render, is_valid, c * 2);
        }
    } else if (ws_size >= Q24_B + FTAB_B) {
        unsigned* ptexu = (unsigned*)d_ws;
        float4*   ftab  = (float4*)((char*)d_ws + Q24_B);
        build_ftab<<<(F + 255) / 256, 256, 0, stream>>>(face_uv, vertex_uv, ftab, F);
        for (int c = 0; c < 2; ++c) {
            pack_quad_chunk<false><<<(2 * HWT) / 256, 256, 0, stream>>>(uvmap, ptexu, c * 2);
            render_chunk<false><<<HHALF / 256, 256, 0, stream>>>(
                ptexu, ftab, bary, pix_to_face, bkg, F, render, is_valid, c * 2);
        }
    } else {
        uvrender_direct<<<2048, 256, 0, stream>>>(
            bary, uvmap, vertex_uv, bkg, pix_to_face, face_uv, F,
            render, is_valid);
    }
}